// Round 16
// baseline (172.423 us; speedup 1.0000x reference)
//
#include <hip/hip_runtime.h>
#include <hip/hip_bf16.h>
#include <cstdint>
#include <cstddef>

// ---------------- problem constants ----------------
#define BATCH  4
#define SEQ    1024
#define NHEAD  16
#define DHEAD  64
#define DMODEL 1024
#define NROWS  4096          // BATCH*SEQ
#define BH     64            // BATCH*NHEAD
#define NRTOT  65536         // BH*SEQ
#define CLIPV  0.999999f
#define PEXP   65.0f         // d_intrinsic + alpha

// u16 quantization of t = -65*lg, t in [-133.27, 0]
#define QOFF   133.5f
#define QK_    490.8988764f           // 65535/133.5
#define QINV   0.0020370716f          // 133.5/65535
#define QC     65535.5f               // QOFF*QK_ + 0.5 (round-nearest)

typedef _Float16 h16;
typedef _Float16 half8 __attribute__((ext_vector_type(8)));
typedef _Float16 half4 __attribute__((ext_vector_type(4)));
typedef __fp16   fp16x2 __attribute__((ext_vector_type(2)));
typedef float    f32x4 __attribute__((ext_vector_type(4)));
typedef unsigned uint2v __attribute__((ext_vector_type(2)));

typedef const __attribute__((address_space(1))) void gas_void;
typedef __attribute__((address_space(3))) void las_void;
#define GLOAD_LDS16(g, l) \
    __builtin_amdgcn_global_load_lds((gas_void*)(g), (las_void*)(l), 16, 0, 0)

// lg = log2(1 + acos(clip(d))).  score = 2^(-65*lg).
// Common case |d|<0.7 (dots of independent unit vectors in 64-dim are
// ~N(0,1/64)): acos(d) = pi/2 - d*P(d^2) (odd Taylor to x^13, |err|<=1e-4)
// -- NO sqrt, cutting trans ops 3->2 per score.  Rare |d|>=0.7 lanes take
// the exec-masked sqrt path (AS 4.4.45 minimax).
__device__ __forceinline__ float spfns_lg(float d) {
    d = __builtin_amdgcn_fmed3f(d, -CLIPV, CLIPV);
    float a = fabsf(d);
    float g;
    if (a < 0.7f) {
        float u = d * d;
        float p = 0.0173541f;           // x^13
        p = fmaf(p, u, 0.0223722f);     // x^11
        p = fmaf(p, u, 0.0303819f);     // x^9
        p = fmaf(p, u, 0.0446429f);     // x^7
        p = fmaf(p, u, 0.0750000f);     // x^5
        p = fmaf(p, u, 0.1666667f);     // x^3
        p = fmaf(p, u, 1.0f);           // x^1
        g = fmaf(-d, p, 1.57079632679f);  // pi/2 - asin(d)
    } else {
        float s = __builtin_amdgcn_sqrtf(1.0f - a);
        float p = -0.0187293f;
        p = fmaf(p, a,  0.0742610f);
        p = fmaf(p, a, -0.2121144f);
        p = fmaf(p, a,  1.5707288f);
        float r = s * p;
        g = (d >= 0.0f) ? r : (3.14159265358979f - r);
    }
    return __builtin_amdgcn_logf(1.0f + g);
}

__device__ __forceinline__ unsigned pk_h2(float lo, float hi) {
    fp16x2 v = __builtin_amdgcn_cvt_pkrtz(lo, hi);
    return __builtin_bit_cast(unsigned, v);
}

__device__ __forceinline__ half8 h8_zero() {
    half8 z;
    #pragma unroll
    for (int e = 0; e < 8; ++e) z[e] = (h16)0.f;
    return z;
}

// ---------------------------------------------------------------------------
// K1: x f32 -> xh f16
// ---------------------------------------------------------------------------
__global__ __launch_bounds__(256) void cvt_x(const float* __restrict__ x,
                                             h16* __restrict__ xh)
{
    size_t i = ((size_t)blockIdx.x * 256 + threadIdx.x) * 8;
    float4 a = *reinterpret_cast<const float4*>(&x[i]);
    float4 b = *reinterpret_cast<const float4*>(&x[i + 4]);
    half8 o;
    o[0]=(h16)a.x; o[1]=(h16)a.y; o[2]=(h16)a.z; o[3]=(h16)a.w;
    o[4]=(h16)b.x; o[5]=(h16)b.y; o[6]=(h16)b.z; o[7]=(h16)b.w;
    *reinterpret_cast<half8*>(&xh[i]) = o;
}

// ---------------------------------------------------------------------------
// K2: transpose+convert W [k][d] f32 -> Wt [d][k] f16.  z selects matrix.
// ---------------------------------------------------------------------------
__global__ __launch_bounds__(256) void wtrans(const float* __restrict__ wq,
                                              const float* __restrict__ wk,
                                              const float* __restrict__ wv,
                                              const float* __restrict__ wo,
                                              h16* __restrict__ wt3,
                                              h16* __restrict__ wot)
{
    __shared__ float T[64][65];
    const int k0 = blockIdx.x * 64, d0 = blockIdx.y * 64, z = blockIdx.z;
    const float* src = (z==0)?wq:(z==1)?wk:(z==2)?wv:wo;
    h16* dst = (z==3) ? wot : (wt3 + (size_t)z * 1024 * 1024);
    const int t = threadIdx.x;

    #pragma unroll
    for (int p = 0; p < 4; ++p) {
        int k = (t >> 4) + p * 16;
        int c = (t & 15) * 4;
        float4 v = *reinterpret_cast<const float4*>(&src[(size_t)(k0 + k) * 1024 + d0 + c]);
        T[c + 0][k] = v.x; T[c + 1][k] = v.y; T[c + 2][k] = v.z; T[c + 3][k] = v.w;
    }
    __syncthreads();
    #pragma unroll
    for (int p = 0; p < 2; ++p) {
        int dl = (t >> 3) + p * 32;
        int c  = (t & 7) * 8;
        half8 o;
        #pragma unroll
        for (int e = 0; e < 8; ++e) o[e] = (h16)T[dl][c + e];
        *reinterpret_cast<half8*>(&dst[(size_t)(d0 + dl) * 1024 + k0 + c]) = o;
    }
}

// ---------------------------------------------------------------------------
// K3: C = A(f16) @ Bt(f16)^T + bias.  128x128 tile, BK=64, 4 waves (2x2).
// LDS XOR-swizzle (T2, rule #21-safe): linear gload_lds dest, pre-permuted
// global source column, same involution on fragment reads.
// ---------------------------------------------------------------------------
__global__ __launch_bounds__(256) void gemm_f16(const h16* __restrict__ A,
                                                const h16* __restrict__ Bt,
                                                const float* __restrict__ b0,
                                                const float* __restrict__ b1,
                                                const float* __restrict__ b2,
                                                h16* __restrict__ oq,
                                                h16* __restrict__ ok,
                                                h16* __restrict__ ovt,
                                                float* __restrict__ of32,
                                                int mode)
{
    __shared__ __align__(16) h16 As[128][64];
    __shared__ __align__(16) h16 Bs[128][64];
    const int n0 = blockIdx.x * 128, d0 = blockIdx.y * 128;
    const int t = threadIdx.x, l = t & 63, w = t >> 6;
    const int wr = (w >> 1) * 64, wc = (w & 1) * 64;
    const int lr = l >> 3;
    const int lc8s = ((l & 7) ^ (lr & 7)) * 8;   // swizzled source column

    f32x4 acc[4][4];
    #pragma unroll
    for (int i = 0; i < 4; ++i)
        #pragma unroll
        for (int j = 0; j < 4; ++j) acc[i][j] = (f32x4){0.f,0.f,0.f,0.f};

    for (int k0 = 0; k0 < 1024; k0 += 64) {
        __syncthreads();
        #pragma unroll
        for (int q = 0; q < 4; ++q) {
            int r = w * 32 + q * 8;
            GLOAD_LDS16(&A[(size_t)(n0 + r + lr) * 1024 + k0 + lc8s], &As[r][0]);
            GLOAD_LDS16(&Bt[(size_t)(d0 + r + lr) * 1024 + k0 + lc8s], &Bs[r][0]);
        }
        __syncthreads();
        #pragma unroll
        for (int kk = 0; kk < 2; ++kk) {
            half8 a[4], b[4];
            #pragma unroll
            for (int fi = 0; fi < 4; ++fi) {
                int row = wr + fi*16 + (l & 15);
                int sl  = (((l >> 4) + kk*4) ^ (row & 7)) * 8;
                a[fi] = *reinterpret_cast<const half8*>(&As[row][sl]);
            }
            #pragma unroll
            for (int fj = 0; fj < 4; ++fj) {
                int row = wc + fj*16 + (l & 15);
                int sl  = (((l >> 4) + kk*4) ^ (row & 7)) * 8;
                b[fj] = *reinterpret_cast<const half8*>(&Bs[row][sl]);
            }
            #pragma unroll
            for (int fi = 0; fi < 4; ++fi)
                #pragma unroll
                for (int fj = 0; fj < 4; ++fj)
                    acc[fi][fj] = __builtin_amdgcn_mfma_f32_16x16x32_f16(a[fi], b[fj], acc[fi][fj], 0, 0, 0);
        }
    }

    if (mode == 0) {
        const int dbase = d0 + wc;             // multiple of 64
        const int mat = dbase >> 10, d1b = dbase & 1023, h = d1b >> 6;
        const float* bp = (mat == 0) ? b0 : (mat == 1) ? b1 : b2;
        #pragma unroll
        for (int fi = 0; fi < 4; ++fi) {
            float vals[4][4];   // [fj][rr]
            #pragma unroll
            for (int fj = 0; fj < 4; ++fj) {
                float bias = bp[d1b + fj * 16 + (l & 15)];
                #pragma unroll
                for (int rr = 0; rr < 4; ++rr) vals[fj][rr] = acc[fi][fj][rr] + bias;
            }
            if (mat < 2) {
                float ss[4];
                #pragma unroll
                for (int rr = 0; rr < 4; ++rr)
                    ss[rr] = vals[0][rr]*vals[0][rr] + vals[1][rr]*vals[1][rr]
                           + vals[2][rr]*vals[2][rr] + vals[3][rr]*vals[3][rr];
                #pragma unroll
                for (int off = 1; off < 16; off <<= 1) {
                    #pragma unroll
                    for (int rr = 0; rr < 4; ++rr) ss[rr] += __shfl_xor(ss[rr], off);
                }
                #pragma unroll
                for (int rr = 0; rr < 4; ++rr) {
                    float sc = __builtin_amdgcn_rcpf(
                        fmaxf(__builtin_amdgcn_sqrtf(ss[rr]), 1e-12f));
                    #pragma unroll
                    for (int fj = 0; fj < 4; ++fj) vals[fj][rr] *= sc;
                }
            }
            const int s0n = n0 + wr + fi * 16 + ((l >> 4) << 2);
            #pragma unroll
            for (int fj = 0; fj < 4; ++fj) {
                int dh = fj * 16 + (l & 15);
                if (mat == 2) {
                    int b = s0n >> 10, s0 = s0n & 1023;
                    half4 o;
                    #pragma unroll
                    for (int rr = 0; rr < 4; ++rr) o[rr] = (h16)vals[fj][rr];
                    *reinterpret_cast<half4*>(&ovt[(((size_t)(b * NHEAD + h)) * DHEAD + dh) * SEQ + s0]) = o;
                } else {
                    h16* dst = (mat == 0) ? oq : ok;
                    #pragma unroll
                    for (int rr = 0; rr < 4; ++rr) {
                        int n = s0n + rr, b = n >> 10, s = n & 1023;
                        dst[(((size_t)(b * NHEAD + h)) * SEQ + s) * DHEAD + dh] = (h16)vals[fj][rr];
                    }
                }
            }
        }
    } else {
        #pragma unroll
        for (int fi = 0; fi < 4; ++fi) {
            #pragma unroll
            for (int fj = 0; fj < 4; ++fj) {
                int d = d0 + wc + fj * 16 + (l & 15);
                int s0n = n0 + wr + fi * 16 + ((l >> 4) << 2);
                float bias = b0[d];
                #pragma unroll
                for (int rr = 0; rr < 4; ++rr) {
                    int n = s0n + rr;
                    of32[(size_t)n * DMODEL + d] = acc[fi][fj][rr] + bias;
                }
            }
        }
    }
}

// ---------------------------------------------------------------------------
// K5 pass A (swapped MFMA, barrier-free it-loop, 32-wide j-tile): per
// (jt32, bh) with XCD swizzle.  Incremental Sw stores.  Row-min via plain
// stores to per-jt planes rm2[32][NRTOT] (no atomics, no init needed).
// ---------------------------------------------------------------------------
template<int CACHED>
__global__ __launch_bounds__(256) void passA(const h16* __restrict__ qh,
                                             const h16* __restrict__ kh,
                                             float* __restrict__ nc,
                                             float* __restrict__ rm2,
                                             int* __restrict__ gacc,
                                             unsigned short* __restrict__ Sw)
{
    __shared__ __align__(16) h16 Ks[32][72];
    __shared__ float red[4][32];
    const int t = threadIdx.x, l = t & 63, w = t >> 6;
    const int id  = blockIdx.y * 32 + blockIdx.x;
    const int nid = (id & 7) * 256 + (id >> 3);
    const int jt = nid & 31, bh = nid >> 5;
    const int j0 = jt * 32;

    {
        int r = t >> 3, c = (t & 7) * 8;
        *reinterpret_cast<half8*>(&Ks[r][c]) =
            *reinterpret_cast<const half8*>(&kh[(((size_t)bh * SEQ) + j0 + r) * DHEAD + c]);
    }
    __syncthreads();

    half8 kfr[2][2];
    #pragma unroll
    for (int f = 0; f < 2; ++f)
        #pragma unroll
        for (int kk = 0; kk < 2; ++kk)
            kfr[f][kk] = *reinterpret_cast<const half8*>(&Ks[f*16 + (l & 15)][((l >> 4) * 8) + kk * 32]);

    float ncacc[8];
    #pragma unroll
    for (int x = 0; x < 8; ++x) ncacc[x] = 0.f;

    // incremental Sw write pointers (layout identical to 64-tile scheme)
    unsigned short* sp[2] = {nullptr, nullptr};
    if (CACHED) {
        size_t base = ((((size_t)(bh*16 + (jt >> 1))*16)*16 + w*4 + (jt & 1)*2) << 8)
                      + (size_t)l*4;
        sp[0] = Sw + base;
        sp[1] = sp[0] + 256;
    }
    // row-min plane for this jt
    float* rmp = rm2 + (size_t)jt * NRTOT + (size_t)bh * SEQ + w*16;

    const h16* qb = qh + ((size_t)bh * SEQ + w*16 + (l & 15)) * DHEAD + ((l >> 4) * 8);
    half8 nq0 = *reinterpret_cast<const half8*>(qb);
    half8 nq1 = *reinterpret_cast<const half8*>(qb + 32);

    #pragma unroll 2
    for (int it = 0; it < 16; ++it) {
        half8 aq0 = nq0, aq1 = nq1;
        if (it < 15) {
            const h16* qn = qb + (size_t)(it + 1) * 64 * DHEAD;
            nq0 = *reinterpret_cast<const half8*>(qn);
            nq1 = *reinterpret_cast<const half8*>(qn + 32);
        }

        float mloc = 1e30f;
        #pragma unroll
        for (int f = 0; f < 2; ++f) {
            f32x4 cfr = (f32x4){0.f,0.f,0.f,0.f};
            cfr = __builtin_amdgcn_mfma_f32_16x16x32_f16(kfr[f][0], aq0, cfr, 0, 0, 0);
            cfr = __builtin_amdgcn_mfma_f32_16x16x32_f16(kfr[f][1], aq1, cfr, 0, 0, 0);
            unsigned uq[4];
            #pragma unroll
            for (int rr = 0; rr < 4; ++rr) {
                float lg = spfns_lg(cfr[rr]);
                float tt = lg * (-PEXP);
                ncacc[f*4 + rr] += __builtin_amdgcn_exp2f(tt);
                mloc = fminf(mloc, lg);
                if (CACHED) uq[rr] = (unsigned)fmaf(tt, QK_, QC);
            }
            if (CACHED) {
                uint2v pkw;
                pkw[0] = uq[0] | (uq[1] << 16);
                pkw[1] = uq[2] | (uq[3] << 16);
                *reinterpret_cast<uint2v*>(sp[f]) = pkw;
            }
        }
        if (CACHED) { sp[0] += 4096; sp[1] += 4096; }
        mloc = fminf(mloc, __shfl_xor(mloc, 16));
        mloc = fminf(mloc, __shfl_xor(mloc, 32));
        if (l < 16) rmp[it*64 + l] = mloc;
    }

    #pragma unroll
    for (int x = 0; x < 8; ++x) {
        #pragma unroll
        for (int off = 1; off < 16; off <<= 1)
            ncacc[x] += __shfl_xor(ncacc[x], off);
    }
    if ((l & 15) == 0) {
        #pragma unroll
        for (int x = 0; x < 8; ++x)
            red[w][(x >> 2) * 16 + (l >> 4) * 4 + (x & 3)] = ncacc[x];
    }
    __syncthreads();
    if (t < 32) {
        float v = red[0][t] + red[1][t] + red[2][t] + red[3][t];
        nc[(size_t)bh * SEQ + j0 + t] = v;
        atomicAdd(gacc, (int)rintf(__builtin_amdgcn_logf(v) * 64.0f));
    }
}

// ---------------------------------------------------------------------------
// K6: lcr = log2 shift for columns; lrm = -65 * min over the 32 rm2 planes.
// ---------------------------------------------------------------------------
__global__ __launch_bounds__(256) void ncprep(const float* __restrict__ nc,
                                              const float* __restrict__ rm2,
                                              const int* __restrict__ gacc,
                                              float* __restrict__ lcr,
                                              float* __restrict__ lrm)
{
    int i = blockIdx.x * 256 + threadIdx.x;
    float Lm = (float)(*gacc) / (65536.0f * 64.0f);   // mean log2(nc)
    lcr[i] = -0.5f * (__builtin_amdgcn_logf(nc[i]) - Lm);
    float m = rm2[i];
    #pragma unroll
    for (int jt = 1; jt < 32; ++jt)
        m = fminf(m, rm2[(size_t)jt * NRTOT + i]);
    lrm[i] = -PEXP * m;
}

// ---------------------------------------------------------------------------
// K7a pass B, CACHED: double-buffered LDS V (ONE barrier per chunk) with T14
// async split.  S decode replaces QK^T.  PV + ones-column MFMA denominator.
// ---------------------------------------------------------------------------
__global__ __launch_bounds__(256) void passB_c(const h16* __restrict__ vt,
                                               const float* __restrict__ lcr,
                                               const float* __restrict__ lrm,
                                               const unsigned short* __restrict__ Sw,
                                               h16* __restrict__ aoh)
{
    __shared__ __align__(16) h16 Vs[2][64][72];
    __shared__ __align__(16) h16 Ps[4][16][72];
    const int t = threadIdx.x, l = t & 63, w = t >> 6;
    const int id  = blockIdx.y * 16 + blockIdx.x;
    const int nid = (id & 7) * 128 + (id >> 3);
    const int it = nid & 15, bh = nid >> 4;
    const int i0 = it * 64;

    const float nlr = -lrm[(size_t)bh * SEQ + i0 + w*16 + (l & 15)] - QOFF;

    half8 ones8 = h8_zero();
    if ((l & 15) == 0) {
        #pragma unroll
        for (int e = 0; e < 8; ++e) ones8[e] = (h16)1.0f;
    }

    f32x4 pv[4];
    #pragma unroll
    for (int fd = 0; fd < 4; ++fd) pv[fd] = (f32x4){0.f,0.f,0.f,0.f};
    f32x4 pvden = (f32x4){0.f,0.f,0.f,0.f};

    const int sr = t >> 3, sc = (t & 7) * 8;
    const h16* vsrc = vt + ((size_t)bh * DHEAD + sr) * SEQ + sc;
    const float* lc_base = lcr + (size_t)bh * SEQ + (l >> 4) * 4;

    auto s_ptr = [&](int jc2, int fj) -> const uint2v* {
        size_t sidx = (((((size_t)(bh*16 + jc2)*16 + it)*4 + w)*4 + fj) << 8) + (size_t)l*4;
        return reinterpret_cast<const uint2v*>(&Sw[sidx]);
    };

    // pre-loop loads for chunk 0
    half8 vr0 = *reinterpret_cast<const half8*>(vsrc);
    half8 vr1 = *reinterpret_cast<const half8*>(vsrc + (size_t)32 * SEQ);
    uint2v sv[4];
    float4 lc[4];
    #pragma unroll
    for (int fj = 0; fj < 4; ++fj) {
        sv[fj] = *s_ptr(0, fj);
        lc[fj] = *reinterpret_cast<const float4*>(&lc_base[fj*16]);
    }

    int pb = 0;
    for (int jc = 0; jc < 16; ++jc) {
        // stage this chunk's V into buffer pb (safe: all waves passed the
        // previous barrier => all reads of Vs[pb] complete)
        *reinterpret_cast<half8*>(&Vs[pb][sr][sc])      = vr0;
        *reinterpret_cast<half8*>(&Vs[pb][sr + 32][sc]) = vr1;

        // T14: issue next chunk's V loads now (consumed next iteration)
        if (jc < 15) {
            const h16* vn = vsrc + (jc + 1) * 64;
            vr0 = *reinterpret_cast<const half8*>(vn);
            vr1 = *reinterpret_cast<const half8*>(vn + (size_t)32 * SEQ);
        }
        __syncthreads();   // Vs[pb] visible to all waves

        // decode S -> packed Ps writes (uses this chunk's sv/lc)
        #pragma unroll
        for (int fj = 0; fj < 4; ++fj) {
            float u0 = (float)(sv[fj][0] & 0xffffu), u1 = (float)(sv[fj][0] >> 16);
            float u2 = (float)(sv[fj][1] & 0xffffu), u3 = (float)(sv[fj][1] >> 16);
            float pp0 = __builtin_amdgcn_exp2f(fmaf(u0, QINV, lc[fj].x + nlr));
            float pp1 = __builtin_amdgcn_exp2f(fmaf(u1, QINV, lc[fj].y + nlr));
            float pp2 = __builtin_amdgcn_exp2f(fmaf(u2, QINV, lc[fj].z + nlr));
            float pp3 = __builtin_amdgcn_exp2f(fmaf(u3, QINV, lc[fj].w + nlr));
            uint2v pk;
            pk[0] = pk_h2(pp0, pp1);
            pk[1] = pk_h2(pp2, pp3);
            *reinterpret_cast<uint2v*>(&Ps[w][l & 15][fj*16 + (l >> 4) * 4]) = pk;
        }
        // prefetch next chunk's S + lcr (overlaps PV)
        if (jc < 15) {
            #pragma unroll
            for (int fj = 0; fj < 4; ++fj) {
                sv[fj] = *s_ptr(jc + 1, fj);
                lc[fj] = *reinterpret_cast<const float4*>(&lc_base[(jc + 1)*64 + fj*16]);
            }
        }
        // no barrier: Ps[w] is wave-local

        half8 pa0 = *reinterpret_cast<const half8*>(&Ps[w][l & 15][((l >> 4) * 8)]);
        half8 pa1 = *reinterpret_cast<const half8*>(&Ps[w][l & 15][((l >> 4) * 8) + 32]);
        #pragma unroll
        for (int fd = 0; fd < 4; ++fd) {
            half8 vb0 = *reinterpret_cast<const half8*>(&Vs[pb][fd*16 + (l & 15)][((l >> 4) * 8)]);
            half8 vb1 = *reinterpret_cast<const half8*>(&Vs[pb][fd*16 + (l & 15)][((l >> 4) * 8) + 32]);
            pv[fd] = __builtin_amdgcn_mfma_f32_16x16x32_f16(pa0, vb0, pv[fd], 0, 0, 0);
            pv[fd] = __builtin_amdgcn_mfma_f32_16x16x32_f16(pa1, vb1, pv[fd], 0, 0, 0);
        }
        pvden = __builtin_amdgcn_mfma_f32_16x16x32_f16(pa0, ones8, pvden, 0, 0, 0);
        pvden = __builtin_amdgcn_mfma_f32_16x16x32_f16(pa1, ones8, pvden, 0, 0, 0);
        pb ^= 1;
    }

    const int b = bh >> 4, h = bh & 15;
    #pragma unroll
    for (int rr = 0; rr < 4; ++rr) {
        float ds = __shfl(pvden[rr], l & 48);
        float inv = __builtin_amdgcn_rcpf(ds);
        int s = i0 + w * 16 + ((l >> 4) << 2) + rr;
        #pragma unroll
        for (int fd = 0; fd < 4; ++fd) {
            aoh[((size_t)(b * SEQ + s)) * DMODEL + h * DHEAD + fd * 16 + (l & 15)] =
                (h16)(pv[fd][rr] * inv);
        }
    }
}

// ---------------------------------------------------------------------------
// K7b pass B, fallback (no ws room): full recompute, LDS-staged.
// ---------------------------------------------------------------------------
__global__ __launch_bounds__(256) void passB_r(const h16* __restrict__ qh,
                                               const h16* __restrict__ kh,
                                               const h16* __restrict__ vt,
                                               const float* __restrict__ lcr,
                                               const float* __restrict__ lrm,
                                               h16* __restrict__ aoh)
{
    __shared__ __align__(16) h16 Ks[64][72];
    __shared__ __align__(16) h16 Vs[64][72];
    __shared__ __align__(16) h16 Ps[4][16][72];
    __shared__ float lcr_s[64];
    __shared__ float lrm_s[64];

    const int it = blockIdx.x, bh = blockIdx.y;
    const int i0 = it * 64;
    const int t = threadIdx.x, l = t & 63, w = t >> 6;
    h16* Pflat = &Ps[0][0][0];

    #pragma unroll
    for (int p = 0; p < 2; ++p) {
        int r = (t >> 3) + p * 32, c = (t & 7) * 8;
        *reinterpret_cast<half8*>(&Pflat[r * 72 + c]) =
            *reinterpret_cast<const half8*>(&qh[(((size_t)bh * SEQ) + i0 + r) * DHEAD + c]);
    }
    if (t < 64) lrm_s[t] = lrm[(size_t)bh * SEQ + i0 + t];
    __syncthreads();

    half8 aq0 = *reinterpret_cast<const half8*>(&Pflat[(w*16 + (l & 15)) * 72 + ((l >> 4) * 8)]);
    half8 aq1 = *reinterpret_cast<const half8*>(&Pflat[(w*16 + (l & 15)) * 72 + ((l >> 4) * 8) + 32]);
    const float nlr = -lrm_s[w*16 + (l & 15)];

    half8 ones8 = h8_zero();
    if ((l & 15) == 0) {
        #pragma unroll
        for (int e = 0; e < 8; ++e) ones8[e] = (h16)1.0f;
    }

    f32x4 pv[4];
    #pragma unroll
    for (int fd = 0; fd < 4; ++fd) pv[fd] = (f32x4){0.f,0.f,0.f,0.f};
    f32x4 pvden = (f32x4){0.f,0.f,0.f,0.f};

    for (int jc = 0; jc < 16; ++jc) {
        const int j0 = jc * 64;
        __syncthreads();
        #pragma unroll
        for (int p = 0; p < 2; ++p) {
            int r = (t >> 3) + p * 32, c = (t & 7) * 8;
            *reinterpret_cast<half8*>(&Ks[r][c]) =
                *reinterpret_cast<const half8*>(&kh[(((size_t)bh * SEQ) + j0 + r) * DHEAD + c]);
            *reinterpret_cast<half8*>(&Vs[r][c]) =
                *reinterpret_cast<const half8*>(&vt[(((size_t)bh * DHEAD) + r) * SEQ + j0 + c]);
        }
        if (t < 64) lcr_s[t] = lcr[(size_t)bh * SEQ + j0 + t];
        __syncthreads();

        #pragma unroll
        for (int fj = 0; fj < 4; ++fj) {
            half8 kb0 = *reinterpret_cast<const half8*>(&Ks[fj*16 + (l & 15)][((l >> 4) * 8)]);
            half8 kb1 = *reinterpret_cast<const half8*>(&Ks[fj*16 + (l & 15)][((l >> 4) * 8) + 32]);
            f32x4 cfr = (f32x4){0.f,0.f,0.f,0.f};
            cfr = __builtin_amdgcn_mfma_f32_16x16x32_f16(kb0, aq0, cfr, 0, 0, 0);
            cfr = __builtin_amdgcn_mfma_f32_16x16x32_f16(kb1, aq1, cfr, 0, 0, 0);
            float4 lc4 = *reinterpret_cast<const float4*>(&lcr_s[fj*16 + (l >> 4) * 4]);
            float pp0 = __builtin_amdgcn_exp2f(fmaf(spfns_lg(cfr[0]), -PEXP, lc4.x + nlr));
            float pp1 = __builtin_amdgcn_exp2f(fmaf(spfns_lg(cfr[1]), -PEXP, lc4.y + nlr));
            float pp2 = __builtin_amdgcn_exp2f(fmaf(spfns_lg(cfr[2]), -PEXP, lc4.z + nlr));
            float pp3 = __builtin_amdgcn_exp2f(fmaf(spfns_lg(cfr[3]), -PEXP, lc4.w + nlr));
            uint2v pk;
            pk[0] = pk_h2(pp0, pp1);
            pk[1] = pk_h2(pp2, pp3);
            *reinterpret_cast<uint2v*>(&Ps[w][l & 15][fj*16 + (l >> 4) * 4]) = pk;
        }

        half8 pa0 = *reinterpret_cast<const half8*>(&Ps[w][l & 15][((l >> 4) * 8)]);
        half8 pa1 = *reinterpret_cast<const half8*>(&Ps[w][l & 15][((l >> 4) * 8) + 32]);
        #pragma unroll
        for (int fd = 0; fd < 4; ++fd) {
            half8 vb0 = *reinterpret_cast<const half8*>(&Vs[fd*16 + (l & 15)][((l >> 4) * 8)]);
            half8 vb1 = *reinterpret_cast<const half8*>(&Vs[fd*16 + (l & 15)][((l >> 4) * 8) + 32]);
            pv[fd] = __builtin_amdgcn_mfma_f32_16x16x32_f16(pa0, vb0, pv[fd], 0, 0, 0);
            pv[fd] = __builtin_amdgcn_mfma_f32_16x16x32_f16(pa1, vb1, pv[fd], 0, 0, 0);
        }
        pvden = __builtin_amdgcn_mfma_f32_16x16x32_f16(pa0, ones8, pvden, 0, 0, 0);
        pvden = __builtin_amdgcn_mfma_f32_16x16x32_f16(pa1, ones8, pvden, 0, 0, 0);
    }

    const int b = bh >> 4, h = bh & 15;
    #pragma unroll
    for (int rr = 0; rr < 4; ++rr) {
        float ds = __shfl(pvden[rr], l & 48);
        float inv = __builtin_amdgcn_rcpf(ds);
        int s = i0 + w * 16 + ((l >> 4) << 2) + rr;
        #pragma unroll
        for (int fd = 0; fd < 4; ++fd) {
            aoh[((size_t)(b * SEQ + s)) * DMODEL + h * DHEAD + fd * 16 + (l & 15)] =
                (h16)(pv[fd][rr] * inv);
        }
    }
}

// ---------------------------------------------------------------------------
extern "C" void kernel_launch(void* const* d_in, const int* in_sizes, int n_in,
                              void* d_out, int out_size, void* d_ws, size_t ws_size,
                              hipStream_t stream)
{
    (void)in_sizes; (void)n_in; (void)out_size;
    const float* x  = (const float*)d_in[0];
    const float* wq = (const float*)d_in[1];
    const float* bq = (const float*)d_in[2];
    const float* wk = (const float*)d_in[3];
    const float* bk = (const float*)d_in[4];
    const float* wv = (const float*)d_in[5];
    const float* bv = (const float*)d_in[6];
    const float* wo = (const float*)d_in[7];
    const float* bo = (const float*)d_in[8];
    float* out = (float*)d_out;

    h16* ws16 = (h16*)d_ws;
    const size_t NX  = (size_t)NROWS * DMODEL;
    const size_t NW3 = (size_t)3 * DMODEL * DMODEL;
    const size_t NW1 = (size_t)DMODEL * DMODEL;
    const size_t NH  = (size_t)BH * SEQ * DHEAD;
    h16* xh  = ws16;
    h16* wt3 = xh  + NX;
    h16* wot = wt3 + NW3;
    h16* qh  = wot + NW1;
    h16* kh  = qh  + NH;
    h16* vt  = kh  + NH;
    h16* aoh = vt  + NH;
    float* nc  = (float*)(aoh + NX);
    float* lcr = nc  + NRTOT;
    float* lrm = lcr + NRTOT;
    int* gacc  = (int*)(lrm + NRTOT);
    float* rm2 = (float*)(gacc + 64);          // 32 * NRTOT f32 = 8 MB

    size_t used = (size_t)((char*)(rm2 + 32 * (size_t)NRTOT) - (char*)d_ws);
    used = (used + 255) & ~(size_t)255;
    unsigned short* Sw = (unsigned short*)((char*)d_ws + used);
    const size_t SBYTES = (size_t)BH * SEQ * SEQ * 2;   // 134,217,728
    const bool cache = (ws_size >= used + SBYTES);

    hipMemsetAsync(gacc, 0, sizeof(int), stream);

    cvt_x<<<2048, 256, 0, stream>>>(x, xh);
    wtrans<<<dim3(16, 16, 4), 256, 0, stream>>>(wq, wk, wv, wo, wt3, wot);

    gemm_f16<<<dim3(32, 24), 256, 0, stream>>>(xh, wt3, bq, bk, bv,
                                               qh, kh, vt, nullptr, 0);

    if (cache) {
        passA<1><<<dim3(32, BH), 256, 0, stream>>>(qh, kh, nc, rm2, gacc, Sw);
        ncprep<<<256, 256, 0, stream>>>(nc, rm2, gacc, lcr, lrm);
        passB_c<<<dim3(16, BH), 256, 0, stream>>>(vt, lcr, lrm, Sw, aoh);
    } else {
        passA<0><<<dim3(32, BH), 256, 0, stream>>>(qh, kh, nc, rm2, gacc, Sw);
        ncprep<<<256, 256, 0, stream>>>(nc, rm2, gacc, lcr, lrm);
        passB_r<<<dim3(16, BH), 256, 0, stream>>>(qh, kh, vt, lcr, lrm, aoh);
    }

    gemm_f16<<<dim3(32, 8), 256, 0, stream>>>(aoh, wot, bo, nullptr, nullptr,
                                              nullptr, nullptr, nullptr, out, 1);
}

// Round 17
// 166.269 us; speedup vs baseline: 1.0370x; 1.0370x over previous
//
#include <hip/hip_runtime.h>
#include <hip/hip_bf16.h>
#include <cstdint>
#include <cstddef>

// ---------------- problem constants ----------------
#define BATCH  4
#define SEQ    1024
#define NHEAD  16
#define DHEAD  64
#define DMODEL 1024
#define NROWS  4096          // BATCH*SEQ
#define BH     64            // BATCH*NHEAD
#define NRTOT  65536         // BH*SEQ
#define CLIPV  0.999999f
#define PEXP   65.0f         // d_intrinsic + alpha

// u16 quantization of t = -65*lg, t in [-133.27, 0]
#define QOFF   133.5f
#define QK_    490.8988764f           // 65535/133.5
#define QINV   0.0020370716f          // 133.5/65535
#define QC     65535.5f               // QOFF*QK_ + 0.5 (round-nearest)

typedef _Float16 h16;
typedef _Float16 half8 __attribute__((ext_vector_type(8)));
typedef _Float16 half4 __attribute__((ext_vector_type(4)));
typedef __fp16   fp16x2 __attribute__((ext_vector_type(2)));
typedef float    f32x4 __attribute__((ext_vector_type(4)));
typedef unsigned uint2v __attribute__((ext_vector_type(2)));

typedef const __attribute__((address_space(1))) void gas_void;
typedef __attribute__((address_space(3))) void las_void;
#define GLOAD_LDS16(g, l) \
    __builtin_amdgcn_global_load_lds((gas_void*)(g), (las_void*)(l), 16, 0, 0)

// lg = log2(1 + acos(clip(d))).  score = 2^(-65*lg).
// acos via AS 4.4.45 minimax (|err|<=6.8e-5): acos(a)=sqrt(1-a)*p3(a).
__device__ __forceinline__ float spfns_lg(float d) {
    d = __builtin_amdgcn_fmed3f(d, -CLIPV, CLIPV);
    float a = fabsf(d);
    float s = __builtin_amdgcn_sqrtf(1.0f - a);
    float p = -0.0187293f;
    p = fmaf(p, a,  0.0742610f);
    p = fmaf(p, a, -0.2121144f);
    p = fmaf(p, a,  1.5707288f);
    float r = s * p;
    float g = (d >= 0.0f) ? r : (3.14159265358979f - r);
    return __builtin_amdgcn_logf(1.0f + g);
}

__device__ __forceinline__ unsigned pk_h2(float lo, float hi) {
    fp16x2 v = __builtin_amdgcn_cvt_pkrtz(lo, hi);
    return __builtin_bit_cast(unsigned, v);
}

__device__ __forceinline__ half8 h8_zero() {
    half8 z;
    #pragma unroll
    for (int e = 0; e < 8; ++e) z[e] = (h16)0.f;
    return z;
}

// ---------------------------------------------------------------------------
// K1: x f32 -> xh f16
// ---------------------------------------------------------------------------
__global__ __launch_bounds__(256) void cvt_x(const float* __restrict__ x,
                                             h16* __restrict__ xh)
{
    size_t i = ((size_t)blockIdx.x * 256 + threadIdx.x) * 8;
    float4 a = *reinterpret_cast<const float4*>(&x[i]);
    float4 b = *reinterpret_cast<const float4*>(&x[i + 4]);
    half8 o;
    o[0]=(h16)a.x; o[1]=(h16)a.y; o[2]=(h16)a.z; o[3]=(h16)a.w;
    o[4]=(h16)b.x; o[5]=(h16)b.y; o[6]=(h16)b.z; o[7]=(h16)b.w;
    *reinterpret_cast<half8*>(&xh[i]) = o;
}

// ---------------------------------------------------------------------------
// K2: transpose+convert W [k][d] f32 -> Wt [d][k] f16.  z selects matrix.
// ---------------------------------------------------------------------------
__global__ __launch_bounds__(256) void wtrans(const float* __restrict__ wq,
                                              const float* __restrict__ wk,
                                              const float* __restrict__ wv,
                                              const float* __restrict__ wo,
                                              h16* __restrict__ wt3,
                                              h16* __restrict__ wot)
{
    __shared__ float T[64][65];
    const int k0 = blockIdx.x * 64, d0 = blockIdx.y * 64, z = blockIdx.z;
    const float* src = (z==0)?wq:(z==1)?wk:(z==2)?wv:wo;
    h16* dst = (z==3) ? wot : (wt3 + (size_t)z * 1024 * 1024);
    const int t = threadIdx.x;

    #pragma unroll
    for (int p = 0; p < 4; ++p) {
        int k = (t >> 4) + p * 16;
        int c = (t & 15) * 4;
        float4 v = *reinterpret_cast<const float4*>(&src[(size_t)(k0 + k) * 1024 + d0 + c]);
        T[c + 0][k] = v.x; T[c + 1][k] = v.y; T[c + 2][k] = v.z; T[c + 3][k] = v.w;
    }
    __syncthreads();
    #pragma unroll
    for (int p = 0; p < 2; ++p) {
        int dl = (t >> 3) + p * 32;
        int c  = (t & 7) * 8;
        half8 o;
        #pragma unroll
        for (int e = 0; e < 8; ++e) o[e] = (h16)T[dl][c + e];
        *reinterpret_cast<half8*>(&dst[(size_t)(d0 + dl) * 1024 + k0 + c]) = o;
    }
}

// ---------------------------------------------------------------------------
// K3: C = A(f16) @ Bt(f16)^T + bias.  128x128 tile, BK=64, 4 waves (2x2).
// LDS XOR-swizzle (T2, rule #21-safe): linear gload_lds dest, pre-permuted
// global source column, same involution on fragment reads.
// ---------------------------------------------------------------------------
__global__ __launch_bounds__(256) void gemm_f16(const h16* __restrict__ A,
                                                const h16* __restrict__ Bt,
                                                const float* __restrict__ b0,
                                                const float* __restrict__ b1,
                                                const float* __restrict__ b2,
                                                h16* __restrict__ oq,
                                                h16* __restrict__ ok,
                                                h16* __restrict__ ovt,
                                                float* __restrict__ of32,
                                                int mode)
{
    __shared__ __align__(16) h16 As[128][64];
    __shared__ __align__(16) h16 Bs[128][64];
    const int n0 = blockIdx.x * 128, d0 = blockIdx.y * 128;
    const int t = threadIdx.x, l = t & 63, w = t >> 6;
    const int wr = (w >> 1) * 64, wc = (w & 1) * 64;
    const int lr = l >> 3;
    const int lc8s = ((l & 7) ^ (lr & 7)) * 8;   // swizzled source column

    f32x4 acc[4][4];
    #pragma unroll
    for (int i = 0; i < 4; ++i)
        #pragma unroll
        for (int j = 0; j < 4; ++j) acc[i][j] = (f32x4){0.f,0.f,0.f,0.f};

    for (int k0 = 0; k0 < 1024; k0 += 64) {
        __syncthreads();
        #pragma unroll
        for (int q = 0; q < 4; ++q) {
            int r = w * 32 + q * 8;
            GLOAD_LDS16(&A[(size_t)(n0 + r + lr) * 1024 + k0 + lc8s], &As[r][0]);
            GLOAD_LDS16(&Bt[(size_t)(d0 + r + lr) * 1024 + k0 + lc8s], &Bs[r][0]);
        }
        __syncthreads();
        #pragma unroll
        for (int kk = 0; kk < 2; ++kk) {
            half8 a[4], b[4];
            #pragma unroll
            for (int fi = 0; fi < 4; ++fi) {
                int row = wr + fi*16 + (l & 15);
                int sl  = (((l >> 4) + kk*4) ^ (row & 7)) * 8;
                a[fi] = *reinterpret_cast<const half8*>(&As[row][sl]);
            }
            #pragma unroll
            for (int fj = 0; fj < 4; ++fj) {
                int row = wc + fj*16 + (l & 15);
                int sl  = (((l >> 4) + kk*4) ^ (row & 7)) * 8;
                b[fj] = *reinterpret_cast<const half8*>(&Bs[row][sl]);
            }
            #pragma unroll
            for (int fi = 0; fi < 4; ++fi)
                #pragma unroll
                for (int fj = 0; fj < 4; ++fj)
                    acc[fi][fj] = __builtin_amdgcn_mfma_f32_16x16x32_f16(a[fi], b[fj], acc[fi][fj], 0, 0, 0);
        }
    }

    if (mode == 0) {
        const int dbase = d0 + wc;             // multiple of 64
        const int mat = dbase >> 10, d1b = dbase & 1023, h = d1b >> 6;
        const float* bp = (mat == 0) ? b0 : (mat == 1) ? b1 : b2;
        #pragma unroll
        for (int fi = 0; fi < 4; ++fi) {
            float vals[4][4];   // [fj][rr]
            #pragma unroll
            for (int fj = 0; fj < 4; ++fj) {
                float bias = bp[d1b + fj * 16 + (l & 15)];
                #pragma unroll
                for (int rr = 0; rr < 4; ++rr) vals[fj][rr] = acc[fi][fj][rr] + bias;
            }
            if (mat < 2) {
                float ss[4];
                #pragma unroll
                for (int rr = 0; rr < 4; ++rr)
                    ss[rr] = vals[0][rr]*vals[0][rr] + vals[1][rr]*vals[1][rr]
                           + vals[2][rr]*vals[2][rr] + vals[3][rr]*vals[3][rr];
                #pragma unroll
                for (int off = 1; off < 16; off <<= 1) {
                    #pragma unroll
                    for (int rr = 0; rr < 4; ++rr) ss[rr] += __shfl_xor(ss[rr], off);
                }
                #pragma unroll
                for (int rr = 0; rr < 4; ++rr) {
                    float sc = __builtin_amdgcn_rcpf(
                        fmaxf(__builtin_amdgcn_sqrtf(ss[rr]), 1e-12f));
                    #pragma unroll
                    for (int fj = 0; fj < 4; ++fj) vals[fj][rr] *= sc;
                }
            }
            const int s0n = n0 + wr + fi * 16 + ((l >> 4) << 2);
            #pragma unroll
            for (int fj = 0; fj < 4; ++fj) {
                int dh = fj * 16 + (l & 15);
                if (mat == 2) {
                    int b = s0n >> 10, s0 = s0n & 1023;
                    half4 o;
                    #pragma unroll
                    for (int rr = 0; rr < 4; ++rr) o[rr] = (h16)vals[fj][rr];
                    *reinterpret_cast<half4*>(&ovt[(((size_t)(b * NHEAD + h)) * DHEAD + dh) * SEQ + s0]) = o;
                } else {
                    h16* dst = (mat == 0) ? oq : ok;
                    #pragma unroll
                    for (int rr = 0; rr < 4; ++rr) {
                        int n = s0n + rr, b = n >> 10, s = n & 1023;
                        dst[(((size_t)(b * NHEAD + h)) * SEQ + s) * DHEAD + dh] = (h16)vals[fj][rr];
                    }
                }
            }
        }
    } else {
        #pragma unroll
        for (int fi = 0; fi < 4; ++fi) {
            #pragma unroll
            for (int fj = 0; fj < 4; ++fj) {
                int d = d0 + wc + fj * 16 + (l & 15);
                int s0n = n0 + wr + fi * 16 + ((l >> 4) << 2);
                float bias = b0[d];
                #pragma unroll
                for (int rr = 0; rr < 4; ++rr) {
                    int n = s0n + rr;
                    of32[(size_t)n * DMODEL + d] = acc[fi][fj][rr] + bias;
                }
            }
        }
    }
}

// ---------------------------------------------------------------------------
// K5 pass A (swapped MFMA, barrier-free it-loop, 32-wide j-tile): per
// (jt32, bh) with XCD swizzle.  Incremental Sw stores.  Row-min via plain
// stores to per-jt planes rm2[32][NRTOT] (no atomics, no init needed).
// ---------------------------------------------------------------------------
template<int CACHED>
__global__ __launch_bounds__(256) void passA(const h16* __restrict__ qh,
                                             const h16* __restrict__ kh,
                                             float* __restrict__ nc,
                                             float* __restrict__ rm2,
                                             int* __restrict__ gacc,
                                             unsigned short* __restrict__ Sw)
{
    __shared__ __align__(16) h16 Ks[32][72];
    __shared__ float red[4][32];
    const int t = threadIdx.x, l = t & 63, w = t >> 6;
    const int id  = blockIdx.y * 32 + blockIdx.x;
    const int nid = (id & 7) * 256 + (id >> 3);
    const int jt = nid & 31, bh = nid >> 5;
    const int j0 = jt * 32;

    {
        int r = t >> 3, c = (t & 7) * 8;
        *reinterpret_cast<half8*>(&Ks[r][c]) =
            *reinterpret_cast<const half8*>(&kh[(((size_t)bh * SEQ) + j0 + r) * DHEAD + c]);
    }
    __syncthreads();

    half8 kfr[2][2];
    #pragma unroll
    for (int f = 0; f < 2; ++f)
        #pragma unroll
        for (int kk = 0; kk < 2; ++kk)
            kfr[f][kk] = *reinterpret_cast<const half8*>(&Ks[f*16 + (l & 15)][((l >> 4) * 8) + kk * 32]);

    float ncacc[8];
    #pragma unroll
    for (int x = 0; x < 8; ++x) ncacc[x] = 0.f;

    // incremental Sw write pointers (layout identical to 64-tile scheme)
    unsigned short* sp[2] = {nullptr, nullptr};
    if (CACHED) {
        size_t base = ((((size_t)(bh*16 + (jt >> 1))*16)*16 + w*4 + (jt & 1)*2) << 8)
                      + (size_t)l*4;
        sp[0] = Sw + base;
        sp[1] = sp[0] + 256;
    }
    // row-min plane for this jt
    float* rmp = rm2 + (size_t)jt * NRTOT + (size_t)bh * SEQ + w*16;

    const h16* qb = qh + ((size_t)bh * SEQ + w*16 + (l & 15)) * DHEAD + ((l >> 4) * 8);
    half8 nq0 = *reinterpret_cast<const half8*>(qb);
    half8 nq1 = *reinterpret_cast<const half8*>(qb + 32);

    #pragma unroll 2
    for (int it = 0; it < 16; ++it) {
        half8 aq0 = nq0, aq1 = nq1;
        if (it < 15) {
            const h16* qn = qb + (size_t)(it + 1) * 64 * DHEAD;
            nq0 = *reinterpret_cast<const half8*>(qn);
            nq1 = *reinterpret_cast<const half8*>(qn + 32);
        }

        float mloc = 1e30f;
        #pragma unroll
        for (int f = 0; f < 2; ++f) {
            f32x4 cfr = (f32x4){0.f,0.f,0.f,0.f};
            cfr = __builtin_amdgcn_mfma_f32_16x16x32_f16(kfr[f][0], aq0, cfr, 0, 0, 0);
            cfr = __builtin_amdgcn_mfma_f32_16x16x32_f16(kfr[f][1], aq1, cfr, 0, 0, 0);
            unsigned uq[4];
            #pragma unroll
            for (int rr = 0; rr < 4; ++rr) {
                float lg = spfns_lg(cfr[rr]);
                float tt = lg * (-PEXP);
                ncacc[f*4 + rr] += __builtin_amdgcn_exp2f(tt);
                mloc = fminf(mloc, lg);
                if (CACHED) uq[rr] = (unsigned)fmaf(tt, QK_, QC);
            }
            if (CACHED) {
                uint2v pkw;
                pkw[0] = uq[0] | (uq[1] << 16);
                pkw[1] = uq[2] | (uq[3] << 16);
                *reinterpret_cast<uint2v*>(sp[f]) = pkw;
            }
        }
        if (CACHED) { sp[0] += 4096; sp[1] += 4096; }
        mloc = fminf(mloc, __shfl_xor(mloc, 16));
        mloc = fminf(mloc, __shfl_xor(mloc, 32));
        if (l < 16) rmp[it*64 + l] = mloc;
    }

    #pragma unroll
    for (int x = 0; x < 8; ++x) {
        #pragma unroll
        for (int off = 1; off < 16; off <<= 1)
            ncacc[x] += __shfl_xor(ncacc[x], off);
    }
    if ((l & 15) == 0) {
        #pragma unroll
        for (int x = 0; x < 8; ++x)
            red[w][(x >> 2) * 16 + (l >> 4) * 4 + (x & 3)] = ncacc[x];
    }
    __syncthreads();
    if (t < 32) {
        float v = red[0][t] + red[1][t] + red[2][t] + red[3][t];
        nc[(size_t)bh * SEQ + j0 + t] = v;
        atomicAdd(gacc, (int)rintf(__builtin_amdgcn_logf(v) * 64.0f));
    }
}

// ---------------------------------------------------------------------------
// K6: lcr = log2 shift for columns; lrm = -65 * min over the 32 rm2 planes.
// ---------------------------------------------------------------------------
__global__ __launch_bounds__(256) void ncprep(const float* __restrict__ nc,
                                              const float* __restrict__ rm2,
                                              const int* __restrict__ gacc,
                                              float* __restrict__ lcr,
                                              float* __restrict__ lrm)
{
    int i = blockIdx.x * 256 + threadIdx.x;
    float Lm = (float)(*gacc) / (65536.0f * 64.0f);   // mean log2(nc)
    lcr[i] = -0.5f * (__builtin_amdgcn_logf(nc[i]) - Lm);
    float m = rm2[i];
    #pragma unroll
    for (int jt = 1; jt < 32; ++jt)
        m = fminf(m, rm2[(size_t)jt * NRTOT + i]);
    lrm[i] = -PEXP * m;
}

// ---------------------------------------------------------------------------
// K7a pass B, CACHED: double-buffered LDS V (ONE barrier per chunk) with T14
// async split.  S decode replaces QK^T.  PV + ones-column MFMA denominator.
// ---------------------------------------------------------------------------
__global__ __launch_bounds__(256) void passB_c(const h16* __restrict__ vt,
                                               const float* __restrict__ lcr,
                                               const float* __restrict__ lrm,
                                               const unsigned short* __restrict__ Sw,
                                               h16* __restrict__ aoh)
{
    __shared__ __align__(16) h16 Vs[2][64][72];
    __shared__ __align__(16) h16 Ps[4][16][72];
    const int t = threadIdx.x, l = t & 63, w = t >> 6;
    const int id  = blockIdx.y * 16 + blockIdx.x;
    const int nid = (id & 7) * 128 + (id >> 3);
    const int it = nid & 15, bh = nid >> 4;
    const int i0 = it * 64;

    const float nlr = -lrm[(size_t)bh * SEQ + i0 + w*16 + (l & 15)] - QOFF;

    half8 ones8 = h8_zero();
    if ((l & 15) == 0) {
        #pragma unroll
        for (int e = 0; e < 8; ++e) ones8[e] = (h16)1.0f;
    }

    f32x4 pv[4];
    #pragma unroll
    for (int fd = 0; fd < 4; ++fd) pv[fd] = (f32x4){0.f,0.f,0.f,0.f};
    f32x4 pvden = (f32x4){0.f,0.f,0.f,0.f};

    const int sr = t >> 3, sc = (t & 7) * 8;
    const h16* vsrc = vt + ((size_t)bh * DHEAD + sr) * SEQ + sc;
    const float* lc_base = lcr + (size_t)bh * SEQ + (l >> 4) * 4;

    auto s_ptr = [&](int jc2, int fj) -> const uint2v* {
        size_t sidx = (((((size_t)(bh*16 + jc2)*16 + it)*4 + w)*4 + fj) << 8) + (size_t)l*4;
        return reinterpret_cast<const uint2v*>(&Sw[sidx]);
    };

    // pre-loop loads for chunk 0
    half8 vr0 = *reinterpret_cast<const half8*>(vsrc);
    half8 vr1 = *reinterpret_cast<const half8*>(vsrc + (size_t)32 * SEQ);
    uint2v sv[4];
    float4 lc[4];
    #pragma unroll
    for (int fj = 0; fj < 4; ++fj) {
        sv[fj] = *s_ptr(0, fj);
        lc[fj] = *reinterpret_cast<const float4*>(&lc_base[fj*16]);
    }

    int pb = 0;
    for (int jc = 0; jc < 16; ++jc) {
        // stage this chunk's V into buffer pb (safe: all waves passed the
        // previous barrier => all reads of Vs[pb] complete)
        *reinterpret_cast<half8*>(&Vs[pb][sr][sc])      = vr0;
        *reinterpret_cast<half8*>(&Vs[pb][sr + 32][sc]) = vr1;

        // T14: issue next chunk's V loads now (consumed next iteration)
        if (jc < 15) {
            const h16* vn = vsrc + (jc + 1) * 64;
            vr0 = *reinterpret_cast<const half8*>(vn);
            vr1 = *reinterpret_cast<const half8*>(vn + (size_t)32 * SEQ);
        }
        __syncthreads();   // Vs[pb] visible to all waves

        // decode S -> packed Ps writes (uses this chunk's sv/lc)
        #pragma unroll
        for (int fj = 0; fj < 4; ++fj) {
            float u0 = (float)(sv[fj][0] & 0xffffu), u1 = (float)(sv[fj][0] >> 16);
            float u2 = (float)(sv[fj][1] & 0xffffu), u3 = (float)(sv[fj][1] >> 16);
            float pp0 = __builtin_amdgcn_exp2f(fmaf(u0, QINV, lc[fj].x + nlr));
            float pp1 = __builtin_amdgcn_exp2f(fmaf(u1, QINV, lc[fj].y + nlr));
            float pp2 = __builtin_amdgcn_exp2f(fmaf(u2, QINV, lc[fj].z + nlr));
            float pp3 = __builtin_amdgcn_exp2f(fmaf(u3, QINV, lc[fj].w + nlr));
            uint2v pk;
            pk[0] = pk_h2(pp0, pp1);
            pk[1] = pk_h2(pp2, pp3);
            *reinterpret_cast<uint2v*>(&Ps[w][l & 15][fj*16 + (l >> 4) * 4]) = pk;
        }
        // prefetch next chunk's S + lcr (overlaps PV)
        if (jc < 15) {
            #pragma unroll
            for (int fj = 0; fj < 4; ++fj) {
                sv[fj] = *s_ptr(jc + 1, fj);
                lc[fj] = *reinterpret_cast<const float4*>(&lc_base[(jc + 1)*64 + fj*16]);
            }
        }
        // no barrier: Ps[w] is wave-local

        half8 pa0 = *reinterpret_cast<const half8*>(&Ps[w][l & 15][((l >> 4) * 8)]);
        half8 pa1 = *reinterpret_cast<const half8*>(&Ps[w][l & 15][((l >> 4) * 8) + 32]);
        #pragma unroll
        for (int fd = 0; fd < 4; ++fd) {
            half8 vb0 = *reinterpret_cast<const half8*>(&Vs[pb][fd*16 + (l & 15)][((l >> 4) * 8)]);
            half8 vb1 = *reinterpret_cast<const half8*>(&Vs[pb][fd*16 + (l & 15)][((l >> 4) * 8) + 32]);
            pv[fd] = __builtin_amdgcn_mfma_f32_16x16x32_f16(pa0, vb0, pv[fd], 0, 0, 0);
            pv[fd] = __builtin_amdgcn_mfma_f32_16x16x32_f16(pa1, vb1, pv[fd], 0, 0, 0);
        }
        pvden = __builtin_amdgcn_mfma_f32_16x16x32_f16(pa0, ones8, pvden, 0, 0, 0);
        pvden = __builtin_amdgcn_mfma_f32_16x16x32_f16(pa1, ones8, pvden, 0, 0, 0);
        pb ^= 1;
    }

    const int b = bh >> 4, h = bh & 15;
    #pragma unroll
    for (int rr = 0; rr < 4; ++rr) {
        float ds = __shfl(pvden[rr], l & 48);
        float inv = __builtin_amdgcn_rcpf(ds);
        int s = i0 + w * 16 + ((l >> 4) << 2) + rr;
        #pragma unroll
        for (int fd = 0; fd < 4; ++fd) {
            aoh[((size_t)(b * SEQ + s)) * DMODEL + h * DHEAD + fd * 16 + (l & 15)] =
                (h16)(pv[fd][rr] * inv);
        }
    }
}

// ---------------------------------------------------------------------------
// K7b pass B, fallback (no ws room): full recompute, LDS-staged.
// ---------------------------------------------------------------------------
__global__ __launch_bounds__(256) void passB_r(const h16* __restrict__ qh,
                                               const h16* __restrict__ kh,
                                               const h16* __restrict__ vt,
                                               const float* __restrict__ lcr,
                                               const float* __restrict__ lrm,
                                               h16* __restrict__ aoh)
{
    __shared__ __align__(16) h16 Ks[64][72];
    __shared__ __align__(16) h16 Vs[64][72];
    __shared__ __align__(16) h16 Ps[4][16][72];
    __shared__ float lcr_s[64];
    __shared__ float lrm_s[64];

    const int it = blockIdx.x, bh = blockIdx.y;
    const int i0 = it * 64;
    const int t = threadIdx.x, l = t & 63, w = t >> 6;
    h16* Pflat = &Ps[0][0][0];

    #pragma unroll
    for (int p = 0; p < 2; ++p) {
        int r = (t >> 3) + p * 32, c = (t & 7) * 8;
        *reinterpret_cast<half8*>(&Pflat[r * 72 + c]) =
            *reinterpret_cast<const half8*>(&qh[(((size_t)bh * SEQ) + i0 + r) * DHEAD + c]);
    }
    if (t < 64) lrm_s[t] = lrm[(size_t)bh * SEQ + i0 + t];
    __syncthreads();

    half8 aq0 = *reinterpret_cast<const half8*>(&Pflat[(w*16 + (l & 15)) * 72 + ((l >> 4) * 8)]);
    half8 aq1 = *reinterpret_cast<const half8*>(&Pflat[(w*16 + (l & 15)) * 72 + ((l >> 4) * 8) + 32]);
    const float nlr = -lrm_s[w*16 + (l & 15)];

    half8 ones8 = h8_zero();
    if ((l & 15) == 0) {
        #pragma unroll
        for (int e = 0; e < 8; ++e) ones8[e] = (h16)1.0f;
    }

    f32x4 pv[4];
    #pragma unroll
    for (int fd = 0; fd < 4; ++fd) pv[fd] = (f32x4){0.f,0.f,0.f,0.f};
    f32x4 pvden = (f32x4){0.f,0.f,0.f,0.f};

    for (int jc = 0; jc < 16; ++jc) {
        const int j0 = jc * 64;
        __syncthreads();
        #pragma unroll
        for (int p = 0; p < 2; ++p) {
            int r = (t >> 3) + p * 32, c = (t & 7) * 8;
            *reinterpret_cast<half8*>(&Ks[r][c]) =
                *reinterpret_cast<const half8*>(&kh[(((size_t)bh * SEQ) + j0 + r) * DHEAD + c]);
            *reinterpret_cast<half8*>(&Vs[r][c]) =
                *reinterpret_cast<const half8*>(&vt[(((size_t)bh * DHEAD) + r) * SEQ + j0 + c]);
        }
        if (t < 64) lcr_s[t] = lcr[(size_t)bh * SEQ + j0 + t];
        __syncthreads();

        #pragma unroll
        for (int fj = 0; fj < 4; ++fj) {
            half8 kb0 = *reinterpret_cast<const half8*>(&Ks[fj*16 + (l & 15)][((l >> 4) * 8)]);
            half8 kb1 = *reinterpret_cast<const half8*>(&Ks[fj*16 + (l & 15)][((l >> 4) * 8) + 32]);
            f32x4 cfr = (f32x4){0.f,0.f,0.f,0.f};
            cfr = __builtin_amdgcn_mfma_f32_16x16x32_f16(kb0, aq0, cfr, 0, 0, 0);
            cfr = __builtin_amdgcn_mfma_f32_16x16x32_f16(kb1, aq1, cfr, 0, 0, 0);
            float4 lc4 = *reinterpret_cast<const float4*>(&lcr_s[fj*16 + (l >> 4) * 4]);
            float pp0 = __builtin_amdgcn_exp2f(fmaf(spfns_lg(cfr[0]), -PEXP, lc4.x + nlr));
            float pp1 = __builtin_amdgcn_exp2f(fmaf(spfns_lg(cfr[1]), -PEXP, lc4.y + nlr));
            float pp2 = __builtin_amdgcn_exp2f(fmaf(spfns_lg(cfr[2]), -PEXP, lc4.z + nlr));
            float pp3 = __builtin_amdgcn_exp2f(fmaf(spfns_lg(cfr[3]), -PEXP, lc4.w + nlr));
            uint2v pk;
            pk[0] = pk_h2(pp0, pp1);
            pk[1] = pk_h2(pp2, pp3);
            *reinterpret_cast<uint2v*>(&Ps[w][l & 15][fj*16 + (l >> 4) * 4]) = pk;
        }

        half8 pa0 = *reinterpret_cast<const half8*>(&Ps[w][l & 15][((l >> 4) * 8)]);
        half8 pa1 = *reinterpret_cast<const half8*>(&Ps[w][l & 15][((l >> 4) * 8) + 32]);
        #pragma unroll
        for (int fd = 0; fd < 4; ++fd) {
            half8 vb0 = *reinterpret_cast<const half8*>(&Vs[fd*16 + (l & 15)][((l >> 4) * 8)]);
            half8 vb1 = *reinterpret_cast<const half8*>(&Vs[fd*16 + (l & 15)][((l >> 4) * 8) + 32]);
            pv[fd] = __builtin_amdgcn_mfma_f32_16x16x32_f16(pa0, vb0, pv[fd], 0, 0, 0);
            pv[fd] = __builtin_amdgcn_mfma_f32_16x16x32_f16(pa1, vb1, pv[fd], 0, 0, 0);
        }
        pvden = __builtin_amdgcn_mfma_f32_16x16x32_f16(pa0, ones8, pvden, 0, 0, 0);
        pvden = __builtin_amdgcn_mfma_f32_16x16x32_f16(pa1, ones8, pvden, 0, 0, 0);
    }

    const int b = bh >> 4, h = bh & 15;
    #pragma unroll
    for (int rr = 0; rr < 4; ++rr) {
        float ds = __shfl(pvden[rr], l & 48);
        float inv = __builtin_amdgcn_rcpf(ds);
        int s = i0 + w * 16 + ((l >> 4) << 2) + rr;
        #pragma unroll
        for (int fd = 0; fd < 4; ++fd) {
            aoh[((size_t)(b * SEQ + s)) * DMODEL + h * DHEAD + fd * 16 + (l & 15)] =
                (h16)(pv[fd][rr] * inv);
        }
    }
}

// ---------------------------------------------------------------------------
extern "C" void kernel_launch(void* const* d_in, const int* in_sizes, int n_in,
                              void* d_out, int out_size, void* d_ws, size_t ws_size,
                              hipStream_t stream)
{
    (void)in_sizes; (void)n_in; (void)out_size;
    const float* x  = (const float*)d_in[0];
    const float* wq = (const float*)d_in[1];
    const float* bq = (const float*)d_in[2];
    const float* wk = (const float*)d_in[3];
    const float* bk = (const float*)d_in[4];
    const float* wv = (const float*)d_in[5];
    const float* bv = (const float*)d_in[6];
    const float* wo = (const float*)d_in[7];
    const float* bo = (const float*)d_in[8];
    float* out = (float*)d_out;

    h16* ws16 = (h16*)d_ws;
    const size_t NX  = (size_t)NROWS * DMODEL;
    const size_t NW3 = (size_t)3 * DMODEL * DMODEL;
    const size_t NW1 = (size_t)DMODEL * DMODEL;
    const size_t NH  = (size_t)BH * SEQ * DHEAD;
    h16* xh  = ws16;
    h16* wt3 = xh  + NX;
    h16* wot = wt3 + NW3;
    h16* qh  = wot + NW1;
    h16* kh  = qh  + NH;
    h16* vt  = kh  + NH;
    h16* aoh = vt  + NH;
    float* nc  = (float*)(aoh + NX);
    float* lcr = nc  + NRTOT;
    float* lrm = lcr + NRTOT;
    int* gacc  = (int*)(lrm + NRTOT);
    float* rm2 = (float*)(gacc + 64);          // 32 * NRTOT f32 = 8 MB

    size_t used = (size_t)((char*)(rm2 + 32 * (size_t)NRTOT) - (char*)d_ws);
    used = (used + 255) & ~(size_t)255;
    unsigned short* Sw = (unsigned short*)((char*)d_ws + used);
    const size_t SBYTES = (size_t)BH * SEQ * SEQ * 2;   // 134,217,728
    const bool cache = (ws_size >= used + SBYTES);

    hipMemsetAsync(gacc, 0, sizeof(int), stream);

    cvt_x<<<2048, 256, 0, stream>>>(x, xh);
    wtrans<<<dim3(16, 16, 4), 256, 0, stream>>>(wq, wk, wv, wo, wt3, wot);

    gemm_f16<<<dim3(32, 24), 256, 0, stream>>>(xh, wt3, bq, bk, bv,
                                               qh, kh, vt, nullptr, 0);

    if (cache) {
        passA<1><<<dim3(32, BH), 256, 0, stream>>>(qh, kh, nc, rm2, gacc, Sw);
        ncprep<<<256, 256, 0, stream>>>(nc, rm2, gacc, lcr, lrm);
        passB_c<<<dim3(16, BH), 256, 0, stream>>>(vt, lcr, lrm, Sw, aoh);
    } else {
        passA<0><<<dim3(32, BH), 256, 0, stream>>>(qh, kh, nc, rm2, gacc, Sw);
        ncprep<<<256, 256, 0, stream>>>(nc, rm2, gacc, lcr, lrm);
        passB_r<<<dim3(16, BH), 256, 0, stream>>>(qh, kh, vt, lcr, lrm, aoh);
    }

    gemm_f16<<<dim3(32, 8), 256, 0, stream>>>(aoh, wot, bo, nullptr, nullptr,
                                              nullptr, nullptr, nullptr, out, 1);
}